// Round 6
// baseline (205.354 us; speedup 1.0000x reference)
//
#include <hip/hip_runtime.h>
#include <hip/hip_cooperative_groups.h>

namespace cg = cooperative_groups;

// Problem: B=4, A=160000 anchors, G=64 gt boxes.
// outputs (concat flat): labels [B,A] f32, matched_gt_boxes [B,A,4] f32
constexpr int NB = 4;
constexpr int NA = 160000;
constexpr int NG = 64;
constexpr int NBLK = 500;           // co-resident (launch_bounds(256,2) => >=512 capacity)
constexpr int NWAVE = NBLK * 4;     // 2000 waves; 500 per batch; 320 anchors/wave

// ws layout: float pi[NWAVE*NG]; float pd[NWAVE*NG]  (fully written, no init)

// --- exact-rounding helpers -------------------------------------------------
__device__ __forceinline__ float box_area(float x0, float y0, float x1, float y1) {
#pragma clang fp contract(off)
    return (x1 - x0) * (y1 - y0);
}

__device__ __forceinline__ void inter_denom(float gx0, float gy0, float gx1, float gy1, float garea,
                                            float ax0, float ay0, float ax1, float ay1, float aarea,
                                            float& inter, float& denom) {
#pragma clang fp contract(off)
    float ltx = fmaxf(gx0, ax0);
    float lty = fmaxf(gy0, ay0);
    float rbx = fminf(gx1, ax1);
    float rby = fminf(gy1, ay1);
    float w = fmaxf(rbx - ltx, 0.0f);
    float h = fmaxf(rby - lty, 0.0f);
    inter = w * h;
    float s = garea + aarea;        // numpy: area_gt + area_anchor
    denom = s - inter;
}

__device__ __forceinline__ float iou_f(float gx0, float gy0, float gx1, float gy1, float garea,
                                       float ax0, float ay0, float ax1, float ay1, float aarea) {
    float inter, denom;
    inter_denom(gx0, gy0, gx1, gy1, garea, ax0, ay0, ax1, ay1, aarea, inter, denom);
    return inter / denom;           // IEEE fp32 divide
}

// exact i1/d1 > i2/d2 (all >= 0, d > 0): fp32 products in f64 are exact
// (24x24 <= 53 bits) -> REAL ordering; rounding monotone => rounded max of the
// winning pair == max of rounded quotients, and equal reals round identically
// (so any merge order gives the same rounded hi).
__device__ __forceinline__ bool frac_gt(float i1, float d1, float i2, float d2) {
    return (double)i1 * (double)d2 > (double)i2 * (double)d1;
}

// --- single fused cooperative kernel ----------------------------------------
__global__ __launch_bounds__(256, 2) void k_fused(
        const float* __restrict__ anchors, const float* __restrict__ gts,
        const float* __restrict__ scores, const int* __restrict__ confs,
        float* __restrict__ ws,
        float* __restrict__ labels_out, float4* __restrict__ boxes_out) {
    const int tid = threadIdx.x;
    const int lane = tid & 63;
    const int wid = __builtin_amdgcn_readfirstlane(tid >> 6);
    const int j = blockIdx.x;

    float* __restrict__ pi = ws;
    float* __restrict__ pd = ws + NWAVE * NG;

    // ---- phase 1: per-wave partial (inter,denom) max per gt -----------------
    // wave w covers batch b1 = w/500, anchors [widx*320, +320); lane owns gt.
    {
        const int w = j * 4 + wid;              // 0..1999
        const int b1 = w / 500;
        const int widx = w % 500;
        const float4* __restrict__ gt4 = reinterpret_cast<const float4*>(gts) + b1 * NG;
        const float4* __restrict__ anc = reinterpret_cast<const float4*>(anchors) + (size_t)b1 * NA;

        float4 g = gt4[lane];
        float garea = box_area(g.x, g.y, g.z, g.w);

        const int base = widx * 320;
        float bi = 0.0f, bd = 1.0f;             // q = 0
#pragma unroll 8
        for (int i = 0; i < 320; ++i) {
            float4 a = anc[base + i];           // wave-uniform -> s_load
            float aarea = box_area(a.x, a.y, a.z, a.w);
            float in, dn;
            inter_denom(g.x, g.y, g.z, g.w, garea, a.x, a.y, a.z, a.w, aarea, in, dn);
            if (frac_gt(in, dn, bi, bd)) { bi = in; bd = dn; }
        }
        pi[w * NG + lane] = bi;                 // coalesced
        pd[w * NG + lane] = bd;
    }

    cg::this_grid().sync();

    // ---- phase 1.5: reduce 500 partials for this block's batch --------------
    const int b = j & 3;            // phase-2 batch of this block
    const int jb = j >> 2;          // 0..124 (125 block-groups per batch)

    __shared__ float ri[4][NG], rd[4][NG];
    __shared__ float4 sg[NG];
    __shared__ float sga[NG], shi[NG], ssc[NG];
    __shared__ int scf[NG];
    {
        // wave wid reduces partial waves [b*500 + wid*125, +125), lane g
        const int w0 = b * 500 + wid * 125;
        float ci = pi[(size_t)w0 * NG + lane], cd = pd[(size_t)w0 * NG + lane];
#pragma unroll 4
        for (int i = 1; i < 125; ++i) {
            float ni = pi[(size_t)(w0 + i) * NG + lane];    // coalesced dword
            float nd = pd[(size_t)(w0 + i) * NG + lane];
            if (frac_gt(ni, nd, ci, cd)) { ci = ni; cd = nd; }
        }
        ri[wid][lane] = ci;
        rd[wid][lane] = cd;
    }
    __syncthreads();
    if (tid < NG) {
        float ci = ri[0][tid], cd = rd[0][tid];
#pragma unroll
        for (int wv = 1; wv < 4; ++wv) {
            float ni = ri[wv][tid], nd = rd[wv][tid];
            if (frac_gt(ni, nd, ci, cd)) { ci = ni; cd = nd; }
        }
        shi[tid] = ci / cd;                     // single IEEE divide per gt

        float4 gv = reinterpret_cast<const float4*>(gts)[b * NG + tid];
        sg[tid] = gv;
        sga[tid] = box_area(gv.x, gv.y, gv.z, gv.w);
        ssc[tid] = scores[b * NG + tid];
        scf[tid] = confs[b * NG + tid];
    }
    __syncthreads();

    // ---- phase 2: 5 anchors/thread, one gt loop (5x ILP on the divides) -----
    const float4* __restrict__ anc = reinterpret_cast<const float4*>(anchors) + (size_t)b * NA;
    const int a0 = jb * 1280 + tid;             // + k*256, k<5

    float4 av[5];
    float aarea[5], best[5];
    int matches[5];
    bool lowq[5];
#pragma unroll
    for (int k = 0; k < 5; ++k) {
        av[k] = anc[a0 + k * 256];              // coalesced
        aarea[k] = box_area(av[k].x, av[k].y, av[k].z, av[k].w);
        best[k] = -1.0f;                        // all-zero row -> argmax 0
        matches[k] = 0;
        lowq[k] = false;
    }

#pragma unroll 2
    for (int g = 0; g < NG; ++g) {
        float4 gb = sg[g];                      // ds_read_b128, amortized 5x
        float ga = sga[g];
        float hg = shi[g];
#pragma unroll
        for (int k = 0; k < 5; ++k) {
            float v = iou_f(gb.x, gb.y, gb.z, gb.w, ga,
                            av[k].x, av[k].y, av[k].z, av[k].w, aarea[k]);
            if (v > best[k]) { best[k] = v; matches[k] = g; }   // FIRST max
            lowq[k] |= (v == hg);               // bit-exact equality
        }
    }

    const size_t obase = (size_t)b * NA;
#pragma unroll
    for (int k = 0; k < 5; ++k) {
        int m    = (best[k] < 0.3f) ? -1 : ((best[k] < 0.7f) ? -2 : matches[k]);
        int midx = lowq[k] ? matches[k] : m;
        int cl   = (midx < 0) ? 0 : midx;

        float4 mg = sg[cl];
        float  sc = ssc[cl];
        int    cf = scf[cl];

        bool pos = (midx >= 0);
        float lab = pos ? 1.0f : 0.0f;
        lab = fminf(lab, sc);
        if (midx == -1) lab = 0.0f;
        if (midx == -2) lab = -1.0f;
        if (sc < 1.0f && pos) lab = -1.0f;
        if (cf == 0 && pos) lab = -1.0f;

        labels_out[obase + a0 + k * 256] = lab;
        boxes_out[obase + a0 + k * 256] = mg;
    }
}

extern "C" void kernel_launch(void* const* d_in, const int* in_sizes, int n_in,
                              void* d_out, int out_size, void* d_ws, size_t ws_size,
                              hipStream_t stream) {
    const float* anchors = (const float*)d_in[0];   // [B,A,4]
    const float* gts     = (const float*)d_in[1];   // [B,G,4]
    const float* scores  = (const float*)d_in[2];   // [B,G]
    const int*   confs   = (const int*)d_in[3];     // [B,G]

    float* labels_out = (float*)d_out;                              // [B,A]
    float4* boxes_out = (float4*)((float*)d_out + (size_t)NB * NA); // [B,A,4]
    float* ws = (float*)d_ws;                       // pi/pd partials (no init needed)

    void* args[] = {(void*)&anchors, (void*)&gts, (void*)&scores, (void*)&confs,
                    (void*)&ws, (void*)&labels_out, (void*)&boxes_out};
    hipLaunchCooperativeKernel((const void*)k_fused, dim3(NBLK), dim3(256),
                               args, 0, stream);
}

// Round 7
// 144.199 us; speedup vs baseline: 1.4241x; 1.4241x over previous
//
#include <hip/hip_runtime.h>

// Problem: B=4, A=160000 anchors, G=64 gt boxes.
// outputs (concat flat): labels [B,A] f32, matched_gt_boxes [B,A,4] f32
constexpr int NB = 4;
constexpr int NA = 160000;
constexpr int NG = 64;

// ws layout:
//   float hi[NB*NG]    — written ONLY by signed-int atomicMax of IoU bits.
//                        Poison 0xAAAAAAAA is a NEGATIVE int; IoU bits >= 0,
//                        and every hi[g] gets 1000 atomic writes -> no init
//                        node needed (works over poison or zeros alike).
//   float meta[NB*NG*8] — per-gt {x0,y0,x1,y1, garea,0,score,conf_bits},
//                        written by k1 blockIdx.x==0; k2 is stream-ordered.

// --- exact-rounding helpers -------------------------------------------------
// contract(off): stop fma fusion that would change rounding vs numpy.
__device__ __forceinline__ float box_area(float x0, float y0, float x1, float y1) {
#pragma clang fp contract(off)
    return (x1 - x0) * (y1 - y0);
}

__device__ __forceinline__ void inter_denom(float gx0, float gy0, float gx1, float gy1, float garea,
                                            float ax0, float ay0, float ax1, float ay1, float aarea,
                                            float& inter, float& denom) {
#pragma clang fp contract(off)
    float ltx = fmaxf(gx0, ax0);
    float lty = fmaxf(gy0, ay0);
    float rbx = fminf(gx1, ax1);
    float rby = fminf(gy1, ay1);
    float w = fmaxf(rbx - ltx, 0.0f);
    float h = fmaxf(rby - lty, 0.0f);
    inter = w * h;
    float s = garea + aarea;        // numpy: area_gt + area_anchor
    denom = s - inter;
}

__device__ __forceinline__ float iou_f(float gx0, float gy0, float gx1, float gy1, float garea,
                                       float ax0, float ay0, float ax1, float ay1, float aarea) {
    float inter, denom;
    inter_denom(gx0, gy0, gx1, gy1, garea, ax0, ay0, ax1, ay1, aarea, inter, denom);
    return inter / denom;           // IEEE fp32 divide
}

// exact i1/d1 > i2/d2 (all >= 0, d > 0): fp32 products in f64 are exact
// (24x24 <= 53 bits) -> REAL-number ordering. Rounding is monotone, so the
// real-max pair's fp32 quotient == max of per-pair rounded quotients.
__device__ __forceinline__ bool frac_gt(float i1, float d1, float i2, float d2) {
    return (double)i1 * (double)d2 > (double)i2 * (double)d1;
}

// --- kernel 1: highest IoU per gt -------------------------------------------
// grid (1000, NB), block 256 (4 waves); wave handles 40 anchors, lane g owns
// gt g (R3's proven body). NEW: 2-stage software pipeline on the wave-uniform
// anchor loads (prefetch next 8 while computing current 8) to cover the
// HBM-stream latency that held VALUBusy at 55%.
__global__ __launch_bounds__(256) void k_gt_highest(
        const float* __restrict__ anchors, const float* __restrict__ gts,
        const float* __restrict__ scores, const int* __restrict__ confs,
        float* __restrict__ ws) {
    const int b = blockIdx.y;
    const int lane = threadIdx.x & 63;
    const int wid = __builtin_amdgcn_readfirstlane(threadIdx.x >> 6);

    const float4* __restrict__ gt4 = reinterpret_cast<const float4*>(gts) + b * NG;
    const float4* __restrict__ anc = reinterpret_cast<const float4*>(anchors) + (size_t)b * NA;

    float4 g = gt4[lane];
    float garea = box_area(g.x, g.y, g.z, g.w);

    const int base = blockIdx.x * 160 + wid * 40;
    float bi = 0.0f, bd = 1.0f;                     // best (inter,denom): q=0

    float4 buf[2][8];
#pragma unroll
    for (int k = 0; k < 8; ++k) buf[0][k] = anc[base + k];

#pragma unroll
    for (int blk = 0; blk < 5; ++blk) {
        const int cur = blk & 1, nxt = cur ^ 1;
        if (blk < 4) {
#pragma unroll
            for (int k = 0; k < 8; ++k)
                buf[nxt][k] = anc[base + (blk + 1) * 8 + k];    // prefetch
        }
#pragma unroll
        for (int k = 0; k < 8; ++k) {
            float4 a = buf[cur][k];
            float aarea = box_area(a.x, a.y, a.z, a.w);
            float in, dn;
            inter_denom(g.x, g.y, g.z, g.w, garea,
                        a.x, a.y, a.z, a.w, aarea, in, dn);
            if (frac_gt(in, dn, bi, bd)) { bi = in; bd = dn; }
        }
    }

    __shared__ float pi[4][NG], pd[4][NG];
    pi[wid][lane] = bi;
    pd[wid][lane] = bd;
    __syncthreads();
    if (threadIdx.x < NG) {
        float ci = pi[0][threadIdx.x], cd = pd[0][threadIdx.x];
#pragma unroll
        for (int wv = 1; wv < 4; ++wv) {
            float ni = pi[wv][threadIdx.x], nd = pd[wv][threadIdx.x];
            if (frac_gt(ni, nd, ci, cd)) { ci = ni; cd = nd; }
        }
        float m = ci / cd;                          // single IEEE divide
        // IoU >= 0: float order == signed-int order of bits; poison is
        // negative as int, so no init of ws is required.
        atomicMax(reinterpret_cast<int*>(ws) + b * NG + threadIdx.x,
                  __float_as_int(m));
    }

    // block x==0 publishes the per-gt meta table for k2
    if (blockIdx.x == 0 && threadIdx.x < NG) {
        const int gi = threadIdx.x;
        float4 gv = gt4[gi];
        float ga = box_area(gv.x, gv.y, gv.z, gv.w);
        float4* meta4 = reinterpret_cast<float4*>(ws + NB * NG) + (b * NG + gi) * 2;
        meta4[0] = gv;
        meta4[1] = make_float4(ga, 0.0f, scores[b * NG + gi],
                               __int_as_float(confs[b * NG + gi]));
    }
}

// --- kernel 2: per-anchor match + labels + matched boxes --------------------
// grid (313, NB), block 256, TWO anchors/thread (ai, ai+256): 8 independent
// divide chains in flight (unroll 4 x 2) while keeping 5008 waves of TLP.
// Hot loop reads gt meta + hi via UNIFORM global loads (s_load path, zero LDS
// issue); LDS only for the one-time epilogue gather.
__global__ __launch_bounds__(256) void k_assign(
        const float* __restrict__ anchors, const float* __restrict__ ws,
        float* __restrict__ labels_out, float4* __restrict__ boxes_out) {
    const int b = blockIdx.y;
    const float* __restrict__ hi = ws + b * NG;
    const float4* __restrict__ meta4 =
        reinterpret_cast<const float4*>(ws + NB * NG) + (size_t)b * NG * 2;

    __shared__ float4 sbox[NG];
    __shared__ float ssc[NG];
    __shared__ int scf[NG];
    if (threadIdx.x < NG) {
        float4 mA = meta4[threadIdx.x * 2];
        float4 mB = meta4[threadIdx.x * 2 + 1];
        sbox[threadIdx.x] = mA;
        ssc[threadIdx.x] = mB.z;
        scf[threadIdx.x] = __float_as_int(mB.w);
    }
    __syncthreads();

    const int ai0 = blockIdx.x * 512 + threadIdx.x;     // 0..159999 exactly
    const int ai1 = ai0 + 256;                          // may be >= NA
    const bool has1 = (ai1 < NA);
    const float4* __restrict__ anc = reinterpret_cast<const float4*>(anchors) + (size_t)b * NA;
    float4 av0 = anc[ai0];
    float4 av1 = anc[has1 ? ai1 : ai0];
    float aarea0 = box_area(av0.x, av0.y, av0.z, av0.w);
    float aarea1 = box_area(av1.x, av1.y, av1.z, av1.w);

    float best0 = -1.0f, best1 = -1.0f;     // all-zero row -> argmax 0
    int   mat0 = 0, mat1 = 0;
    bool  lowq0 = false, lowq1 = false;
#pragma unroll 4
    for (int g = 0; g < NG; ++g) {
        float4 mA = meta4[g * 2];                       // uniform -> s_load
        float4 mB = meta4[g * 2 + 1];                   // uniform -> s_load
        float hg = hi[g];                               // uniform -> s_load
        float v0 = iou_f(mA.x, mA.y, mA.z, mA.w, mB.x,
                         av0.x, av0.y, av0.z, av0.w, aarea0);
        float v1 = iou_f(mA.x, mA.y, mA.z, mA.w, mB.x,
                         av1.x, av1.y, av1.z, av1.w, aarea1);
        if (v0 > best0) { best0 = v0; mat0 = g; }       // strict > keeps FIRST
        if (v1 > best1) { best1 = v1; mat1 = g; }
        lowq0 |= (v0 == hg);                            // bit-exact equality
        lowq1 |= (v1 == hg);
    }

    const size_t obase = (size_t)b * NA;
#pragma unroll
    for (int k = 0; k < 2; ++k) {
        if (k == 1 && !has1) break;
        float best = k ? best1 : best0;
        int matches = k ? mat1 : mat0;
        bool lowq = k ? lowq1 : lowq0;
        int ai = k ? ai1 : ai0;

        int m    = (best < 0.3f) ? -1 : ((best < 0.7f) ? -2 : matches);
        int midx = lowq ? matches : m;
        int cl   = (midx < 0) ? 0 : midx;

        float4 mg = sbox[cl];
        float  sc = ssc[cl];
        int    cf = scf[cl];

        bool pos = (midx >= 0);
        float lab = pos ? 1.0f : 0.0f;
        lab = fminf(lab, sc);
        if (midx == -1) lab = 0.0f;
        if (midx == -2) lab = -1.0f;
        if (sc < 1.0f && pos) lab = -1.0f;
        if (cf == 0 && pos) lab = -1.0f;

        labels_out[obase + ai] = lab;
        boxes_out[obase + ai] = mg;
    }
}

extern "C" void kernel_launch(void* const* d_in, const int* in_sizes, int n_in,
                              void* d_out, int out_size, void* d_ws, size_t ws_size,
                              hipStream_t stream) {
    const float* anchors = (const float*)d_in[0];   // [B,A,4]
    const float* gts     = (const float*)d_in[1];   // [B,G,4]
    const float* scores  = (const float*)d_in[2];   // [B,G]
    const int*   confs   = (const int*)d_in[3];     // [B,G]

    float* labels_out = (float*)d_out;                              // [B,A]
    float4* boxes_out = (float4*)((float*)d_out + (size_t)NB * NA); // [B,A,4]
    float* ws = (float*)d_ws;

    // NO memset node: poison 0xAAAAAAAA is negative as signed int, so the
    // signed atomicMax of IoU bits (>= 0) in k1 is correct uninitialized.

    dim3 g1(1000, NB), g2(313, NB), blk(256);
    k_gt_highest<<<g1, blk, 0, stream>>>(anchors, gts, scores, confs, ws);
    k_assign<<<g2, blk, 0, stream>>>(anchors, ws, labels_out, boxes_out);
}